// Round 8
// baseline (348.813 us; speedup 1.0000x reference)
//
#include <hip/hip_runtime.h>
#include <hip/hip_bf16.h>
#include <math.h>

#define DM   1024
#define NH   16
#define DH   64
#define DFF  4096
#define BB   2
#define TT   2048
#define MTOK (BB*TT)   // 4096 token rows
#define QS   3072      // fused qkv row stride

typedef unsigned short u16;
typedef unsigned int   u32;
typedef __attribute__((ext_vector_type(8))) __bf16 bf16x8;   // MFMA A/B frag (4 VGPRs)
typedef __attribute__((ext_vector_type(4))) float  f32x4;    // MFMA C/D frag

__device__ inline float bf2f(u16 u) { return __uint_as_float(((u32)u) << 16); }
__device__ inline u16 f2bf(float f) {
  u32 u = __float_as_uint(f);
  u += 0x7FFFu + ((u >> 16) & 1u);   // round-to-nearest-even
  return (u16)(u >> 16);
}
// truncating bf16 pack: low u16 = hi-bits(lo), high u16 = hi-bits(hi). 1 VALU op.
__device__ inline u32 packtrunc(float lo, float hi) {
  return __builtin_amdgcn_perm(__float_as_uint(hi), __float_as_uint(lo), 0x07060302u);
}
__device__ inline float fexp2(float x) { return __builtin_amdgcn_exp2f(x); }

__device__ inline void gload_lds16(const void* g, void* l) {
  __builtin_amdgcn_global_load_lds(
      (const __attribute__((address_space(1))) void*)g,
      (__attribute__((address_space(3))) void*)l,
      16, 0, 0);
}

// ---------------------------------------------------------------------------
// prep: all weight fp32->bf16 conversions + LN1, one dispatch.
// ---------------------------------------------------------------------------
__global__ __launch_bounds__(256) void prep(
    const float* __restrict__ wq, const float* __restrict__ wk, const float* __restrict__ wv,
    const float* __restrict__ wo, const float* __restrict__ w1, const float* __restrict__ w2,
    const float* __restrict__ x, const float* __restrict__ g, const float* __restrict__ be,
    u16* __restrict__ wqkv_b, u16* __restrict__ wo_b, u16* __restrict__ w1_b,
    u16* __restrict__ w2_b, u16* __restrict__ h1)
{
  const int blk = blockIdx.x;
  if (blk < 12288) {
    const float* src; u16* dst; int idx;
    if (blk < 3072) {
      idx = blk * 256 + threadIdx.x;              // f4 index into [3072,1024]
      const int sel = idx >> 18;                  // DM*DM/4 = 2^18
      const int j = idx & 0x3FFFF;
      src = sel == 0 ? wq : (sel == 1 ? wk : wv);
      dst = wqkv_b;
      float4 v = ((const float4*)src)[j];
      ushort4 o; o.x = f2bf(v.x); o.y = f2bf(v.y); o.z = f2bf(v.z); o.w = f2bf(v.w);
      ((ushort4*)dst)[idx] = o;
      return;
    } else if (blk < 4096) { src = wo; dst = wo_b; idx = (blk - 3072) * 256 + threadIdx.x; }
    else if (blk < 8192)   { src = w1; dst = w1_b; idx = (blk - 4096) * 256 + threadIdx.x; }
    else                   { src = w2; dst = w2_b; idx = (blk - 8192) * 256 + threadIdx.x; }
    float4 v = ((const float4*)src)[idx];
    ushort4 o; o.x = f2bf(v.x); o.y = f2bf(v.y); o.z = f2bf(v.z); o.w = f2bf(v.w);
    ((ushort4*)dst)[idx] = o;
    return;
  }
  // ---- LN1: one wave per row ----
  const int w = threadIdx.x >> 6, lane = threadIdx.x & 63;
  const int row = (blk - 12288) * 4 + w;
  const float4* xr = (const float4*)(x + (size_t)row * DM);
  float4 v[4];
  float s = 0.f, s2 = 0.f;
#pragma unroll
  for (int i = 0; i < 4; i++) {
    v[i] = xr[i * 64 + lane];
    s  += v[i].x + v[i].y + v[i].z + v[i].w;
    s2 += v[i].x * v[i].x + v[i].y * v[i].y + v[i].z * v[i].z + v[i].w * v[i].w;
  }
#pragma unroll
  for (int off = 32; off > 0; off >>= 1) {
    s  += __shfl_xor(s,  off);
    s2 += __shfl_xor(s2, off);
  }
  const float mu = s * (1.f / DM);
  const float rs = rsqrtf(s2 * (1.f / DM) - mu * mu + 1e-5f);
  u16* orow = h1 + (size_t)row * DM;
#pragma unroll
  for (int i = 0; i < 4; i++) {
    const float4 gg = ((const float4*)g)[i * 64 + lane];
    const float4 bb = ((const float4*)be)[i * 64 + lane];
    ushort4 o;
    o.x = f2bf((v[i].x - mu) * rs * gg.x + bb.x);
    o.y = f2bf((v[i].y - mu) * rs * gg.y + bb.y);
    o.z = f2bf((v[i].z - mu) * rs * gg.z + bb.z);
    o.w = f2bf((v[i].w - mu) * rs * gg.w + bb.w);
    ((ushort4*)orow)[i * 64 + lane] = o;
  }
}

// ---------------------------------------------------------------------------
// reduce_ln: xmid = x + P0 + P1 (WO split-K partials, bf16); h2 = LN2(xmid).
// ---------------------------------------------------------------------------
__global__ __launch_bounds__(256) void reduce_ln(
    const float* __restrict__ x, const u16* __restrict__ P,
    const float* __restrict__ g, const float* __restrict__ be,
    float* __restrict__ xmid, u16* __restrict__ h2)
{
  const u16* P0 = P;
  const u16* P1 = P + (size_t)MTOK * DM;
  const int w = threadIdx.x >> 6, lane = threadIdx.x & 63;
  const int row = blockIdx.x * 4 + w;
  const size_t roff = (size_t)row * DM;
  float4 v[4];
  float s = 0.f, s2 = 0.f;
#pragma unroll
  for (int i = 0; i < 4; i++) {
    const float4 a = ((const float4*)(x + roff))[i * 64 + lane];
    const ushort4 p = ((const ushort4*)(P0 + roff))[i * 64 + lane];
    const ushort4 qv = ((const ushort4*)(P1 + roff))[i * 64 + lane];
    v[i].x = a.x + bf2f(p.x) + bf2f(qv.x); v[i].y = a.y + bf2f(p.y) + bf2f(qv.y);
    v[i].z = a.z + bf2f(p.z) + bf2f(qv.z); v[i].w = a.w + bf2f(p.w) + bf2f(qv.w);
    ((float4*)(xmid + roff))[i * 64 + lane] = v[i];
    s  += v[i].x + v[i].y + v[i].z + v[i].w;
    s2 += v[i].x * v[i].x + v[i].y * v[i].y + v[i].z * v[i].z + v[i].w * v[i].w;
  }
#pragma unroll
  for (int off = 32; off > 0; off >>= 1) {
    s  += __shfl_xor(s,  off);
    s2 += __shfl_xor(s2, off);
  }
  const float mu = s * (1.f / DM);
  const float rs = rsqrtf(s2 * (1.f / DM) - mu * mu + 1e-5f);
  u16* orow = h2 + roff;
#pragma unroll
  for (int i = 0; i < 4; i++) {
    const float4 gg = ((const float4*)g)[i * 64 + lane];
    const float4 bb = ((const float4*)be)[i * 64 + lane];
    ushort4 o;
    o.x = f2bf((v[i].x - mu) * rs * gg.x + bb.x);
    o.y = f2bf((v[i].y - mu) * rs * gg.y + bb.y);
    o.z = f2bf((v[i].z - mu) * rs * gg.z + bb.z);
    o.w = f2bf((v[i].w - mu) * rs * gg.w + bb.w);
    ((ushort4*)orow)[i * 64 + lane] = o;
  }
}

// ---------------------------------------------------------------------------
// reduce_out: d_out = xmid + Q0 + Q1 + b2  (FF2 bf16 partials, fp32 out)
// ---------------------------------------------------------------------------
__global__ __launch_bounds__(256) void reduce_out(
    const u16* __restrict__ Q, const float* __restrict__ xmid,
    const float* __restrict__ b2, float* __restrict__ out)
{
  const u16* Q0 = Q;
  const u16* Q1 = Q + (size_t)MTOK * DM;
  const int i = blockIdx.x * 256 + threadIdx.x;       // f4 index
  const float4 a = ((const float4*)xmid)[i];
  const ushort4 p = ((const ushort4*)Q0)[i];
  const ushort4 qv = ((const ushort4*)Q1)[i];
  const float4 bb = ((const float4*)b2)[i & (DM / 4 - 1)];
  float4 o;
  o.x = a.x + bf2f(p.x) + bf2f(qv.x) + bb.x;
  o.y = a.y + bf2f(p.y) + bf2f(qv.y) + bb.y;
  o.z = a.z + bf2f(p.z) + bf2f(qv.z) + bb.z;
  o.w = a.w + bf2f(p.w) + bf2f(qv.w) + bb.w;
  ((float4*)out)[i] = o;
}

// ---------------------------------------------------------------------------
// bf16 GEMM (R4 structure): C[M,N] = A[M,K] * Bw[N,K]^T, fp32 accumulate.
// EPI: 0 = bf16 out (cols < scaleN get *oscale); 2 = bf16 out + bias + gelu.
// EPI 0 with vtb != null: column-blocks covering cols >= 2*DM are the V
// projection -> written TRANSPOSED to vt[bh][dh][t] (replaces transpose_v;
// each wave-half covers exactly one head's 64 dh-columns; the 4 acc regs are
// 4 consecutive tokens -> one 8B store).
// ---------------------------------------------------------------------------
template <int EPI, int BN>
__global__ __launch_bounds__(256) void gemm_bt(
    const u16* __restrict__ A, const u16* __restrict__ Bw,
    int M, int N, int K,
    const float* __restrict__ bias,
    u16* __restrict__ outB, float oscale, int scaleN, u16* __restrict__ vtb)
{
  constexpr int NJ = BN / 32;           // MFMA col-tiles per wave
  __shared__ u16 As[128 * 64];
  __shared__ u16 Bs[BN * 64];

  const int tid  = threadIdx.x;
  const int w    = tid >> 6;
  const int lane = tid & 63;
  const int wr   = w >> 1, wc = w & 1;
  const int q    = lane >> 4;    // quad
  const int li   = lane & 15;
  const int rowBase = blockIdx.y * 128;
  const int colBase = blockIdx.x * BN;

  const int lr = lane >> 3;
  const int cs = (lane & 7) ^ lr;
  const u16* Abase = A  + (size_t)(rowBase + lr) * K + cs * 8;
  const u16* Bbase = Bw + (size_t)(colBase + lr) * K + cs * 8;

  f32x4 acc[4][NJ] = {};

  for (int k0 = 0; k0 < K; k0 += 64) {
    __syncthreads();
#pragma unroll
    for (int jj = 0; jj < 4; jj++) {
      const int rb = (w * 4 + jj) * 8;
      gload_lds16(Abase + (size_t)rb * K + k0, &As[rb * 64]);
    }
#pragma unroll
    for (int jj = 0; jj < NJ; jj++) {
      const int rb = (w * NJ + jj) * 8;
      gload_lds16(Bbase + (size_t)rb * K + k0, &Bs[rb * 64]);
    }
    __syncthreads();
#pragma unroll
    for (int kk = 0; kk < 2; kk++) {
      bf16x8 fa[4], fb[NJ];
      const int pos = (kk * 4 + q) ^ (li & 7);
#pragma unroll
      for (int i = 0; i < 4; i++) {
        const int row = wr * 64 + i * 16 + li;
        fa[i] = *(const bf16x8*)&As[row * 64 + pos * 8];
      }
#pragma unroll
      for (int j = 0; j < NJ; j++) {
        const int row = wc * (BN / 2) + j * 16 + li;
        fb[j] = *(const bf16x8*)&Bs[row * 64 + pos * 8];
      }
#pragma unroll
      for (int i = 0; i < 4; i++)
#pragma unroll
        for (int j = 0; j < NJ; j++)
          acc[i][j] = __builtin_amdgcn_mfma_f32_16x16x32_bf16(fa[i], fb[j], acc[i][j], 0, 0, 0);
    }
  }

  if constexpr (EPI == 0) {
    if (BN == 128 && vtb != nullptr && colBase >= 2 * DM) {
      // ---- V projection: store transposed to vt[bh][dh][t] ----
      const int h  = (colBase + wc * 64 - 2 * DM) >> 6;   // BN/2 == DH
      const int b  = rowBase >> 11;                       // 128 | 2048
      const int t0 = (rowBase & (TT - 1)) + wr * 64;
      u16* vbase = vtb + ((size_t)(b * NH + h) * DH) * TT;
#pragma unroll
      for (int j = 0; j < NJ; j++) {
        const int dh = j * 16 + li;
        u16* drow = vbase + (size_t)dh * TT;
#pragma unroll
        for (int i = 0; i < 4; i++) {
          const int t = t0 + i * 16 + q * 4;
          ushort4 o;
          o.x = f2bf(acc[i][j][0]); o.y = f2bf(acc[i][j][1]);
          o.z = f2bf(acc[i][j][2]); o.w = f2bf(acc[i][j][3]);
          *(ushort4*)&drow[t] = o;
        }
      }
      return;
    }
  }

#pragma unroll
  for (int i = 0; i < 4; i++) {
#pragma unroll
    for (int j = 0; j < NJ; j++) {
      const int col = colBase + wc * (BN / 2) + j * 16 + li;
      float bv = 0.f;
      if constexpr (EPI == 2) bv = bias[col];
#pragma unroll
      for (int r = 0; r < 4; r++) {
        const int row = rowBase + wr * 64 + i * 16 + q * 4 + r;
        float v = acc[i][j][r] + bv;
        if constexpr (EPI == 2) {
          // gelu(v) ~= v * sigmoid(1.5957691*v + 0.0713548*v^3)
          const float z = fexp2(-v * (2.302213f + 0.1029625f * v * v));
          v = v * __builtin_amdgcn_rcpf(1.f + z);
        }
        if constexpr (EPI == 0) {
          const float sc = (col < scaleN) ? oscale : 1.f;
          v *= sc;
        }
        outB[(size_t)row * N + col] = f2bf(v);
      }
    }
  }
}

// ---------------------------------------------------------------------------
// Split-K GEMM stage 1: P[z] = A[:, zK..] * Bw[:, zK..]^T  (bf16 partials)
// ---------------------------------------------------------------------------
__global__ __launch_bounds__(256) void gemm_sk(
    const u16* __restrict__ A, const u16* __restrict__ Bw,
    int N, int K, int KLEN, u16* __restrict__ P)
{
  __shared__ u16 As[128 * 64];
  __shared__ u16 Bs[64 * 64];

  const int tid  = threadIdx.x;
  const int w    = tid >> 6;
  const int lane = tid & 63;
  const int wr   = w >> 1, wc = w & 1;
  const int q    = lane >> 4;
  const int li   = lane & 15;
  const int rowBase = blockIdx.y * 128;
  const int colBase = blockIdx.x * 64;
  const int koff = blockIdx.z * KLEN;

  const int lr = lane >> 3;
  const int cs = (lane & 7) ^ lr;
  const u16* Abase = A  + (size_t)(rowBase + lr) * K + koff + cs * 8;
  const u16* Bbase = Bw + (size_t)(colBase + lr) * K + koff + cs * 8;

  f32x4 acc[4][2] = {};

  for (int k0 = 0; k0 < KLEN; k0 += 64) {
    __syncthreads();
#pragma unroll
    for (int jj = 0; jj < 4; jj++) {
      const int rb = (w * 4 + jj) * 8;
      gload_lds16(Abase + (size_t)rb * K + k0, &As[rb * 64]);
    }
#pragma unroll
    for (int jj = 0; jj < 2; jj++) {
      const int rb = (w * 2 + jj) * 8;
      gload_lds16(Bbase + (size_t)rb * K + k0, &Bs[rb * 64]);
    }
    __syncthreads();
#pragma unroll
    for (int kk = 0; kk < 2; kk++) {
      bf16x8 fa[4], fb[2];
      const int pos = (kk * 4 + q) ^ (li & 7);
#pragma unroll
      for (int i = 0; i < 4; i++) {
        const int row = wr * 64 + i * 16 + li;
        fa[i] = *(const bf16x8*)&As[row * 64 + pos * 8];
      }
#pragma unroll
      for (int j = 0; j < 2; j++) {
        const int row = wc * 32 + j * 16 + li;
        fb[j] = *(const bf16x8*)&Bs[row * 64 + pos * 8];
      }
#pragma unroll
      for (int i = 0; i < 4; i++)
#pragma unroll
        for (int j = 0; j < 2; j++)
          acc[i][j] = __builtin_amdgcn_mfma_f32_16x16x32_bf16(fa[i], fb[j], acc[i][j], 0, 0, 0);
    }
  }

  u16* Pz = P + (size_t)blockIdx.z * MTOK * DM;
#pragma unroll
  for (int i = 0; i < 4; i++)
#pragma unroll
    for (int j = 0; j < 2; j++) {
      const int col = colBase + wc * 32 + j * 16 + li;
#pragma unroll
      for (int r = 0; r < 4; r++) {
        const int row = rowBase + wr * 64 + i * 16 + q * 4 + r;
        Pz[(size_t)row * N + col] = f2bf(acc[i][j][r]);
      }
    }
}

// ---------------------------------------------------------------------------
// MFMA flash attention v3 (unchanged from R7). 8 waves x 16 q-rows.
// ---------------------------------------------------------------------------
__global__ __launch_bounds__(512) void attn_mfma(
    const u16* __restrict__ qb, const u16* __restrict__ kb,
    const u16* __restrict__ vt, u16* __restrict__ ob)
{
  __shared__ u16 Ks[2][64 * 64];
  __shared__ u16 Vs[2][64 * 64];
  __shared__ u16 Sh[8 * 16 * 72];

  const int tid = threadIdx.x, w = tid >> 6, lane = tid & 63;
  const int q = lane >> 4, li = lane & 15;
  const int bh = blockIdx.x, b = bh >> 4, h = bh & 15;
  const int q0 = blockIdx.y * 128;
  const int lr8 = lane >> 3, lc8 = lane & 7;

#pragma unroll
  for (int jj = 0; jj < 2; jj++) {
    const int rb = w * 16 + jj * 8;
    const int row = rb + lr8;
    const int cs = lc8 ^ (row & 7);
    gload_lds16(qb + (size_t)(b * TT + q0 + row) * QS + h * DH + cs * 8,
                &Sh[rb * 64]);
  }
  __syncthreads();

  bf16x8 qf[2];
#pragma unroll
  for (int kk = 0; kk < 2; kk++) {
    const int row = w * 16 + li;
    const int pos = (kk * 4 + q) ^ (li & 7);
    qf[kk] = *(const bf16x8*)&Sh[row * 64 + pos * 8];
  }

  auto stage = [&](int buf, int kt) {
    const int rb = w * 8;
    const int row = rb + lr8;
    const int cs = lc8 ^ (row & 7);
    gload_lds16(kb + (size_t)(b * TT + kt + row) * QS + h * DH + cs * 8,
                &Ks[buf][rb * 64]);
    gload_lds16(vt + ((size_t)bh * 64 + row) * TT + kt + cs * 8,
                &Vs[buf][rb * 64]);
  };

  f32x4 ot[4] = {};
  float lsum = 0.f;
  u16* Pw = &Sh[w * 16 * 72];

  stage(0, 0);
  for (int it = 0; it < TT / 64; it++) {
    __syncthreads();
    if (it + 1 < TT / 64) stage((it + 1) & 1, (it + 1) * 64);
    const u16* Kc = Ks[it & 1];
    const u16* Vc = Vs[it & 1];

    f32x4 st[4] = {};
#pragma unroll
    for (int kk = 0; kk < 2; kk++)
#pragma unroll
      for (int i = 0; i < 4; i++) {
        const int pos = (kk * 4 + q) ^ (li & 7);
        const bf16x8 kf = *(const bf16x8*)&Kc[(i * 16 + li) * 64 + pos * 8];
        st[i] = __builtin_amdgcn_mfma_f32_16x16x32_bf16(kf, qf[kk], st[i], 0, 0, 0);
      }

    u32 pk[4][2];
#pragma unroll
    for (int i = 0; i < 4; i++) {
      const float p0 = fexp2(st[i][0]);
      const float p1 = fexp2(st[i][1]);
      const float p2 = fexp2(st[i][2]);
      const float p3 = fexp2(st[i][3]);
      lsum += (p0 + p1) + (p2 + p3);
      pk[i][0] = packtrunc(p0, p1);
      pk[i][1] = packtrunc(p2, p3);
    }

#pragma unroll
    for (int i = 0; i < 4; i++) {
      const int a = li * 72 + i * 16 + q * 4;
      *(u32*)&Pw[a]     = pk[i][0];
      *(u32*)&Pw[a + 2] = pk[i][1];
    }

#pragma unroll
    for (int kk = 0; kk < 2; kk++) {
      const bf16x8 pf = *(const bf16x8*)&Pw[li * 72 + kk * 32 + q * 8];
#pragma unroll
      for (int m = 0; m < 4; m++) {
        const int pos = (kk * 4 + q) ^ (li & 7);
        const bf16x8 vf = *(const bf16x8*)&Vc[(m * 16 + li) * 64 + pos * 8];
        ot[m] = __builtin_amdgcn_mfma_f32_16x16x32_bf16(vf, pf, ot[m], 0, 0, 0);
      }
    }
  }

  float s = lsum;
  s += __shfl_xor(s, 16);
  s += __shfl_xor(s, 32);
  const float inv = 1.f / s;
#pragma unroll
  for (int m = 0; m < 4; m++) {
    const int a = li * 72 + m * 16 + q * 4;
    *(u32*)&Pw[a]     = packtrunc(ot[m][0] * inv, ot[m][1] * inv);
    *(u32*)&Pw[a + 2] = packtrunc(ot[m][2] * inv, ot[m][3] * inv);
  }
#pragma unroll
  for (int pass = 0; pass < 2; pass++) {
    const int row = pass * 8 + lr8;
    const bf16x8 v = *(const bf16x8*)&Pw[row * 72 + lc8 * 8];
    const int token = q0 + w * 16 + row;
    *(bf16x8*)(ob + ((size_t)(b * TT + token) * NH + h) * DH + lc8 * 8) = v;
  }
}

// ---------------------------------------------------------------------------
extern "C" void kernel_launch(void* const* d_in, const int* in_sizes, int n_in,
                              void* d_out, int out_size, void* d_ws, size_t ws_size,
                              hipStream_t stream) {
  const float* x    = (const float*)d_in[0];
  const float* wq   = (const float*)d_in[1];
  const float* wk   = (const float*)d_in[2];
  const float* wv   = (const float*)d_in[3];
  const float* wo   = (const float*)d_in[4];
  const float* w1   = (const float*)d_in[5];
  const float* b1   = (const float*)d_in[6];
  const float* w2   = (const float*)d_in[7];
  const float* b2   = (const float*)d_in[8];
  const float* ln1g = (const float*)d_in[9];
  const float* ln1b = (const float*)d_in[10];
  const float* ln2g = (const float*)d_in[11];
  const float* ln2b = (const float*)d_in[12];

  size_t off = 0;
  char* base = (char*)d_ws;
  auto alloc = [&](size_t bytes) { void* p = base + off; off += bytes; return p; };

  u16* wqkv_b = (u16*)alloc((size_t)3 * DM * DM * 2);   // [3072,1024]
  u16* wo_b   = (u16*)alloc((size_t)DM * DM * 2);
  u16* w1_b   = (u16*)alloc((size_t)DFF * DM * 2);
  u16* w2_b   = (u16*)alloc((size_t)DM * DFF * 2);
  u16* h1     = (u16*)alloc((size_t)MTOK * DM * 2);     // 8 MB
  u16* qkvb   = (u16*)alloc((size_t)MTOK * QS * 2);     // 24 MB
  u16* attn   = (u16*)alloc((size_t)MTOK * DM * 2);     // 8 MB
  u16* h2     = (u16*)alloc((size_t)MTOK * DM * 2);     // 8 MB
  u16* ff1    = (u16*)alloc((size_t)MTOK * DFF * 2);    // 32 MB
  float* xmid = (float*)alloc((size_t)MTOK * DM * 4);
  u16* vtb    = ff1;           // V^T: written by QKV epilogue, read by attn,
                               //   dead before FF1 writes ff1
  u16* woP    = ff1;           // WO bf16 partials (2x8MB): dead before FF1
  u16* ff2P   = h1;            // FF2 bf16 partials (2x8MB: h1+qkvb head, dead)
  (void)ws_size; (void)in_sizes; (void)n_in; (void)out_size;

  // all weight conversions + LN1 in one dispatch
  prep<<<13312, 256, 0, stream>>>(wq, wk, wv, wo, w1, w2, x, ln1g, ln1b,
                                  wqkv_b, wo_b, w1_b, w2_b, h1);

  // fused QKV projection; q cols pre-scaled; V written transposed to vtb
  const float QSCALE = 0.125f * 1.44269504088896340736f;
  gemm_bt<0, 128><<<dim3(QS / 128, MTOK / 128), 256, 0, stream>>>(
      h1, wqkv_b, MTOK, QS, DM, nullptr, qkvb, QSCALE, DM, vtb);

  // MFMA flash attention (8 waves, XCD-grouped)
  attn_mfma<<<dim3(BB * NH, TT / 128), 512, 0, stream>>>(qkvb, qkvb + DM, vtb, attn);

  // out-proj, split-K=2 -> bf16 partials; fused reduce + residual + LN2
  gemm_sk<<<dim3(DM / 64, MTOK / 128, 2), 256, 0, stream>>>(
      attn, wo_b, DM, DM, DM / 2, woP);
  reduce_ln<<<MTOK / 4, 256, 0, stream>>>(x, woP, ln2g, ln2b, xmid, h2);

  // FFN: FF1 (gelu fused), FF2 split-K=2 (bf16 partials) + fused reduce
  gemm_bt<2, 128><<<dim3(DFF / 128, MTOK / 128), 256, 0, stream>>>(
      h2, w1_b, MTOK, DFF, DM, b1, ff1, 1.f, 0, nullptr);
  gemm_sk<<<dim3(DM / 64, MTOK / 128, 2), 256, 0, stream>>>(
      ff1, w2_b, DM, DFF, DFF / 2, ff2P);
  reduce_out<<<MTOK * DM / 4 / 256, 256, 0, stream>>>(ff2P, xmid, b2, (float*)d_out);
}

// Round 9
// 346.034 us; speedup vs baseline: 1.0080x; 1.0080x over previous
//
#include <hip/hip_runtime.h>
#include <hip/hip_bf16.h>
#include <math.h>

#define DM   1024
#define NH   16
#define DH   64
#define DFF  4096
#define BB   2
#define TT   2048
#define MTOK (BB*TT)   // 4096 token rows
#define QS   3072      // fused qkv row stride

typedef unsigned short u16;
typedef unsigned int   u32;
typedef __attribute__((ext_vector_type(8))) __bf16 bf16x8;   // MFMA A/B frag (4 VGPRs)
typedef __attribute__((ext_vector_type(4))) float  f32x4;    // MFMA C/D frag

__device__ inline float bf2f(u16 u) { return __uint_as_float(((u32)u) << 16); }
__device__ inline u16 f2bf(float f) {
  u32 u = __float_as_uint(f);
  u += 0x7FFFu + ((u >> 16) & 1u);   // round-to-nearest-even
  return (u16)(u >> 16);
}
// truncating bf16 pack: low u16 = hi-bits(lo), high u16 = hi-bits(hi). 1 VALU op.
__device__ inline u32 packtrunc(float lo, float hi) {
  return __builtin_amdgcn_perm(__float_as_uint(hi), __float_as_uint(lo), 0x07060302u);
}
__device__ inline float fexp2(float x) { return __builtin_amdgcn_exp2f(x); }

__device__ inline void gload_lds16(const void* g, void* l) {
  __builtin_amdgcn_global_load_lds(
      (const __attribute__((address_space(1))) void*)g,
      (__attribute__((address_space(3))) void*)l,
      16, 0, 0);
}

// ---------------------------------------------------------------------------
// prep: all weight fp32->bf16 conversions + LN1, one dispatch.
// ---------------------------------------------------------------------------
__global__ __launch_bounds__(256) void prep(
    const float* __restrict__ wq, const float* __restrict__ wk, const float* __restrict__ wv,
    const float* __restrict__ wo, const float* __restrict__ w1, const float* __restrict__ w2,
    const float* __restrict__ x, const float* __restrict__ g, const float* __restrict__ be,
    u16* __restrict__ wqkv_b, u16* __restrict__ wo_b, u16* __restrict__ w1_b,
    u16* __restrict__ w2_b, u16* __restrict__ h1)
{
  const int blk = blockIdx.x;
  if (blk < 12288) {
    const float* src; u16* dst; int idx;
    if (blk < 3072) {
      idx = blk * 256 + threadIdx.x;              // f4 index into [3072,1024]
      const int sel = idx >> 18;                  // DM*DM/4 = 2^18
      const int j = idx & 0x3FFFF;
      src = sel == 0 ? wq : (sel == 1 ? wk : wv);
      dst = wqkv_b;
      float4 v = ((const float4*)src)[j];
      ushort4 o; o.x = f2bf(v.x); o.y = f2bf(v.y); o.z = f2bf(v.z); o.w = f2bf(v.w);
      ((ushort4*)dst)[idx] = o;
      return;
    } else if (blk < 4096) { src = wo; dst = wo_b; idx = (blk - 3072) * 256 + threadIdx.x; }
    else if (blk < 8192)   { src = w1; dst = w1_b; idx = (blk - 4096) * 256 + threadIdx.x; }
    else                   { src = w2; dst = w2_b; idx = (blk - 8192) * 256 + threadIdx.x; }
    float4 v = ((const float4*)src)[idx];
    ushort4 o; o.x = f2bf(v.x); o.y = f2bf(v.y); o.z = f2bf(v.z); o.w = f2bf(v.w);
    ((ushort4*)dst)[idx] = o;
    return;
  }
  // ---- LN1: one wave per row ----
  const int w = threadIdx.x >> 6, lane = threadIdx.x & 63;
  const int row = (blk - 12288) * 4 + w;
  const float4* xr = (const float4*)(x + (size_t)row * DM);
  float4 v[4];
  float s = 0.f, s2 = 0.f;
#pragma unroll
  for (int i = 0; i < 4; i++) {
    v[i] = xr[i * 64 + lane];
    s  += v[i].x + v[i].y + v[i].z + v[i].w;
    s2 += v[i].x * v[i].x + v[i].y * v[i].y + v[i].z * v[i].z + v[i].w * v[i].w;
  }
#pragma unroll
  for (int off = 32; off > 0; off >>= 1) {
    s  += __shfl_xor(s,  off);
    s2 += __shfl_xor(s2, off);
  }
  const float mu = s * (1.f / DM);
  const float rs = rsqrtf(s2 * (1.f / DM) - mu * mu + 1e-5f);
  u16* orow = h1 + (size_t)row * DM;
#pragma unroll
  for (int i = 0; i < 4; i++) {
    const float4 gg = ((const float4*)g)[i * 64 + lane];
    const float4 bb = ((const float4*)be)[i * 64 + lane];
    ushort4 o;
    o.x = f2bf((v[i].x - mu) * rs * gg.x + bb.x);
    o.y = f2bf((v[i].y - mu) * rs * gg.y + bb.y);
    o.z = f2bf((v[i].z - mu) * rs * gg.z + bb.z);
    o.w = f2bf((v[i].w - mu) * rs * gg.w + bb.w);
    ((ushort4*)orow)[i * 64 + lane] = o;
  }
}

// ---------------------------------------------------------------------------
// reduce_ln: xmid = x + P0 + P1 (WO split-K partials, bf16); h2 = LN2(xmid).
// ---------------------------------------------------------------------------
__global__ __launch_bounds__(256) void reduce_ln(
    const float* __restrict__ x, const u16* __restrict__ P,
    const float* __restrict__ g, const float* __restrict__ be,
    float* __restrict__ xmid, u16* __restrict__ h2)
{
  const u16* P0 = P;
  const u16* P1 = P + (size_t)MTOK * DM;
  const int w = threadIdx.x >> 6, lane = threadIdx.x & 63;
  const int row = blockIdx.x * 4 + w;
  const size_t roff = (size_t)row * DM;
  float4 v[4];
  float s = 0.f, s2 = 0.f;
#pragma unroll
  for (int i = 0; i < 4; i++) {
    const float4 a = ((const float4*)(x + roff))[i * 64 + lane];
    const ushort4 p = ((const ushort4*)(P0 + roff))[i * 64 + lane];
    const ushort4 qv = ((const ushort4*)(P1 + roff))[i * 64 + lane];
    v[i].x = a.x + bf2f(p.x) + bf2f(qv.x); v[i].y = a.y + bf2f(p.y) + bf2f(qv.y);
    v[i].z = a.z + bf2f(p.z) + bf2f(qv.z); v[i].w = a.w + bf2f(p.w) + bf2f(qv.w);
    ((float4*)(xmid + roff))[i * 64 + lane] = v[i];
    s  += v[i].x + v[i].y + v[i].z + v[i].w;
    s2 += v[i].x * v[i].x + v[i].y * v[i].y + v[i].z * v[i].z + v[i].w * v[i].w;
  }
#pragma unroll
  for (int off = 32; off > 0; off >>= 1) {
    s  += __shfl_xor(s,  off);
    s2 += __shfl_xor(s2, off);
  }
  const float mu = s * (1.f / DM);
  const float rs = rsqrtf(s2 * (1.f / DM) - mu * mu + 1e-5f);
  u16* orow = h2 + roff;
#pragma unroll
  for (int i = 0; i < 4; i++) {
    const float4 gg = ((const float4*)g)[i * 64 + lane];
    const float4 bb = ((const float4*)be)[i * 64 + lane];
    ushort4 o;
    o.x = f2bf((v[i].x - mu) * rs * gg.x + bb.x);
    o.y = f2bf((v[i].y - mu) * rs * gg.y + bb.y);
    o.z = f2bf((v[i].z - mu) * rs * gg.z + bb.z);
    o.w = f2bf((v[i].w - mu) * rs * gg.w + bb.w);
    ((ushort4*)orow)[i * 64 + lane] = o;
  }
}

// ---------------------------------------------------------------------------
// reduce_out: d_out = xmid + Q0 + Q1 + b2  (FF2 bf16 partials, fp32 out)
// ---------------------------------------------------------------------------
__global__ __launch_bounds__(256) void reduce_out(
    const u16* __restrict__ Q, const float* __restrict__ xmid,
    const float* __restrict__ b2, float* __restrict__ out)
{
  const u16* Q0 = Q;
  const u16* Q1 = Q + (size_t)MTOK * DM;
  const int i = blockIdx.x * 256 + threadIdx.x;       // f4 index
  const float4 a = ((const float4*)xmid)[i];
  const ushort4 p = ((const ushort4*)Q0)[i];
  const ushort4 qv = ((const ushort4*)Q1)[i];
  const float4 bb = ((const float4*)b2)[i & (DM / 4 - 1)];
  float4 o;
  o.x = a.x + bf2f(p.x) + bf2f(qv.x) + bb.x;
  o.y = a.y + bf2f(p.y) + bf2f(qv.y) + bb.y;
  o.z = a.z + bf2f(p.z) + bf2f(qv.z) + bb.z;
  o.w = a.w + bf2f(p.w) + bf2f(qv.w) + bb.w;
  ((float4*)out)[i] = o;
}

// ---------------------------------------------------------------------------
// bf16 GEMM (R4 K-loop): C[M,N] = A[M,K] * Bw[N,K]^T, fp32 accumulate.
// 1D grid with XCD-aware decomposition: each XCD owns complete row-panels
// (all GX column-blocks of its y-set), x fastest -> A panel fetched by ONE
// XCD instead of all 8 (R8 counters: FF2-sk FETCH 136MB vs 24MB ideal from
// exactly this cross-XCD A re-fetch). Requires GY % 8 == 0.
// EPI: 0 = bf16 out (cols < scaleN get *oscale); 2 = bf16 out + bias + gelu.
// ---------------------------------------------------------------------------
template <int EPI, int BN>
__global__ __launch_bounds__(256) void gemm_bt(
    const u16* __restrict__ A, const u16* __restrict__ Bw,
    int M, int N, int K,
    const float* __restrict__ bias,
    u16* __restrict__ outB, float oscale, int scaleN, int GX, int GY)
{
  constexpr int NJ = BN / 32;           // MFMA col-tiles per wave
  __shared__ u16 As[128 * 64];
  __shared__ u16 Bs[BN * 64];

  const int flat = blockIdx.x;
  const int xcd  = flat & 7;
  const int j    = flat >> 3;
  const int by   = xcd * (GY >> 3) + j / GX;
  const int bx   = j % GX;

  const int tid  = threadIdx.x;
  const int w    = tid >> 6;
  const int lane = tid & 63;
  const int wr   = w >> 1, wc = w & 1;
  const int q    = lane >> 4;    // quad
  const int li   = lane & 15;
  const int rowBase = by * 128;
  const int colBase = bx * BN;

  const int lr = lane >> 3;
  const int cs = (lane & 7) ^ lr;
  const u16* Abase = A  + (size_t)(rowBase + lr) * K + cs * 8;
  const u16* Bbase = Bw + (size_t)(colBase + lr) * K + cs * 8;

  f32x4 acc[4][NJ] = {};

  for (int k0 = 0; k0 < K; k0 += 64) {
    __syncthreads();
#pragma unroll
    for (int jj = 0; jj < 4; jj++) {
      const int rb = (w * 4 + jj) * 8;
      gload_lds16(Abase + (size_t)rb * K + k0, &As[rb * 64]);
    }
#pragma unroll
    for (int jj = 0; jj < NJ; jj++) {
      const int rb = (w * NJ + jj) * 8;
      gload_lds16(Bbase + (size_t)rb * K + k0, &Bs[rb * 64]);
    }
    __syncthreads();
#pragma unroll
    for (int kk = 0; kk < 2; kk++) {
      bf16x8 fa[4], fb[NJ];
      const int pos = (kk * 4 + q) ^ (li & 7);
#pragma unroll
      for (int i = 0; i < 4; i++) {
        const int row = wr * 64 + i * 16 + li;
        fa[i] = *(const bf16x8*)&As[row * 64 + pos * 8];
      }
#pragma unroll
      for (int j2 = 0; j2 < NJ; j2++) {
        const int row = wc * (BN / 2) + j2 * 16 + li;
        fb[j2] = *(const bf16x8*)&Bs[row * 64 + pos * 8];
      }
#pragma unroll
      for (int i = 0; i < 4; i++)
#pragma unroll
        for (int j2 = 0; j2 < NJ; j2++)
          acc[i][j2] = __builtin_amdgcn_mfma_f32_16x16x32_bf16(fa[i], fb[j2], acc[i][j2], 0, 0, 0);
    }
  }

#pragma unroll
  for (int i = 0; i < 4; i++) {
#pragma unroll
    for (int j2 = 0; j2 < NJ; j2++) {
      const int col = colBase + wc * (BN / 2) + j2 * 16 + li;
      float bv = 0.f;
      if constexpr (EPI == 2) bv = bias[col];
#pragma unroll
      for (int r = 0; r < 4; r++) {
        const int row = rowBase + wr * 64 + i * 16 + q * 4 + r;
        float v = acc[i][j2][r] + bv;
        if constexpr (EPI == 2) {
          // gelu(v) ~= v * sigmoid(1.5957691*v + 0.0713548*v^3)
          const float z = fexp2(-v * (2.302213f + 0.1029625f * v * v));
          v = v * __builtin_amdgcn_rcpf(1.f + z);
        }
        if constexpr (EPI == 0) {
          const float sc = (col < scaleN) ? oscale : 1.f;
          v *= sc;
        }
        outB[(size_t)row * N + col] = f2bf(v);
      }
    }
  }
}

// ---------------------------------------------------------------------------
// Split-K GEMM stage 1: P[z] = A[:, zK..] * Bw[:, zK..]^T  (bf16 partials)
// 1D grid, XCD-aware: panels = (y,z) pairs; GY*2 % 8 == 0.
// ---------------------------------------------------------------------------
__global__ __launch_bounds__(256) void gemm_sk(
    const u16* __restrict__ A, const u16* __restrict__ Bw,
    int N, int K, int KLEN, u16* __restrict__ P, int GX, int GY)
{
  __shared__ u16 As[128 * 64];
  __shared__ u16 Bs[64 * 64];

  const int flat = blockIdx.x;
  const int xcd  = flat & 7;
  const int j    = flat >> 3;
  const int pan  = xcd * ((GY * 2) >> 3) + j / GX;
  const int bx   = j % GX;
  const int by   = pan % GY;
  const int bz   = pan / GY;

  const int tid  = threadIdx.x;
  const int w    = tid >> 6;
  const int lane = tid & 63;
  const int wr   = w >> 1, wc = w & 1;
  const int q    = lane >> 4;
  const int li   = lane & 15;
  const int rowBase = by * 128;
  const int colBase = bx * 64;
  const int koff = bz * KLEN;

  const int lr = lane >> 3;
  const int cs = (lane & 7) ^ lr;
  const u16* Abase = A  + (size_t)(rowBase + lr) * K + koff + cs * 8;
  const u16* Bbase = Bw + (size_t)(colBase + lr) * K + koff + cs * 8;

  f32x4 acc[4][2] = {};

  for (int k0 = 0; k0 < KLEN; k0 += 64) {
    __syncthreads();
#pragma unroll
    for (int jj = 0; jj < 4; jj++) {
      const int rb = (w * 4 + jj) * 8;
      gload_lds16(Abase + (size_t)rb * K + k0, &As[rb * 64]);
    }
#pragma unroll
    for (int jj = 0; jj < 2; jj++) {
      const int rb = (w * 2 + jj) * 8;
      gload_lds16(Bbase + (size_t)rb * K + k0, &Bs[rb * 64]);
    }
    __syncthreads();
#pragma unroll
    for (int kk = 0; kk < 2; kk++) {
      bf16x8 fa[4], fb[2];
      const int pos = (kk * 4 + q) ^ (li & 7);
#pragma unroll
      for (int i = 0; i < 4; i++) {
        const int row = wr * 64 + i * 16 + li;
        fa[i] = *(const bf16x8*)&As[row * 64 + pos * 8];
      }
#pragma unroll
      for (int j2 = 0; j2 < 2; j2++) {
        const int row = wc * 32 + j2 * 16 + li;
        fb[j2] = *(const bf16x8*)&Bs[row * 64 + pos * 8];
      }
#pragma unroll
      for (int i = 0; i < 4; i++)
#pragma unroll
        for (int j2 = 0; j2 < 2; j2++)
          acc[i][j2] = __builtin_amdgcn_mfma_f32_16x16x32_bf16(fa[i], fb[j2], acc[i][j2], 0, 0, 0);
    }
  }

  u16* Pz = P + (size_t)bz * MTOK * DM;
#pragma unroll
  for (int i = 0; i < 4; i++)
#pragma unroll
    for (int j2 = 0; j2 < 2; j2++) {
      const int col = colBase + wc * 32 + j2 * 16 + li;
#pragma unroll
      for (int r = 0; r < 4; r++) {
        const int row = rowBase + wr * 64 + i * 16 + q * 4 + r;
        Pz[(size_t)row * N + col] = f2bf(acc[i][j2][r]);
      }
    }
}

// ---------------------------------------------------------------------------
// V transpose per head: vqkv [token][QS] (v at col h*64..) -> vt [bh][dh][t]
// grid(x = bh, y = t-block) so same-head blocks land on one XCD.
// ---------------------------------------------------------------------------
__global__ __launch_bounds__(256) void transpose_v(
    const u16* __restrict__ vq, u16* __restrict__ vt)
{
  __shared__ u16 t[64][72];
  const int bh = blockIdx.x, b = bh >> 4, h = bh & 15;
  const int t0 = blockIdx.y * 64;
  const int tid = threadIdx.x;
  const int r = tid >> 2, c = (tid & 3) * 16;
  const u16* src = vq + (size_t)(b * TT + t0 + r) * QS + h * DH + c;
#pragma unroll
  for (int i = 0; i < 4; i++)
    *(ushort4*)&t[r][c + i * 4] = ((const ushort4*)src)[i];
  __syncthreads();
  const int dh = tid >> 2, tt = (tid & 3) * 16;
  u16* dst = vt + ((size_t)bh * 64 + dh) * TT + t0 + tt;
#pragma unroll
  for (int i = 0; i < 4; i++) {
    ushort4 o;
    o.x = t[tt + i * 4 + 0][dh]; o.y = t[tt + i * 4 + 1][dh];
    o.z = t[tt + i * 4 + 2][dh]; o.w = t[tt + i * 4 + 3][dh];
    ((ushort4*)dst)[i] = o;
  }
}

// ---------------------------------------------------------------------------
// MFMA flash attention v3 (unchanged). 8 waves x 16 q-rows.
// ---------------------------------------------------------------------------
__global__ __launch_bounds__(512) void attn_mfma(
    const u16* __restrict__ qb, const u16* __restrict__ kb,
    const u16* __restrict__ vt, u16* __restrict__ ob)
{
  __shared__ u16 Ks[2][64 * 64];
  __shared__ u16 Vs[2][64 * 64];
  __shared__ u16 Sh[8 * 16 * 72];

  const int tid = threadIdx.x, w = tid >> 6, lane = tid & 63;
  const int q = lane >> 4, li = lane & 15;
  const int bh = blockIdx.x, b = bh >> 4, h = bh & 15;
  const int q0 = blockIdx.y * 128;
  const int lr8 = lane >> 3, lc8 = lane & 7;

#pragma unroll
  for (int jj = 0; jj < 2; jj++) {
    const int rb = w * 16 + jj * 8;
    const int row = rb + lr8;
    const int cs = lc8 ^ (row & 7);
    gload_lds16(qb + (size_t)(b * TT + q0 + row) * QS + h * DH + cs * 8,
                &Sh[rb * 64]);
  }
  __syncthreads();

  bf16x8 qf[2];
#pragma unroll
  for (int kk = 0; kk < 2; kk++) {
    const int row = w * 16 + li;
    const int pos = (kk * 4 + q) ^ (li & 7);
    qf[kk] = *(const bf16x8*)&Sh[row * 64 + pos * 8];
  }

  auto stage = [&](int buf, int kt) {
    const int rb = w * 8;
    const int row = rb + lr8;
    const int cs = lc8 ^ (row & 7);
    gload_lds16(kb + (size_t)(b * TT + kt + row) * QS + h * DH + cs * 8,
                &Ks[buf][rb * 64]);
    gload_lds16(vt + ((size_t)bh * 64 + row) * TT + kt + cs * 8,
                &Vs[buf][rb * 64]);
  };

  f32x4 ot[4] = {};
  float lsum = 0.f;
  u16* Pw = &Sh[w * 16 * 72];

  stage(0, 0);
  for (int it = 0; it < TT / 64; it++) {
    __syncthreads();
    if (it + 1 < TT / 64) stage((it + 1) & 1, (it + 1) * 64);
    const u16* Kc = Ks[it & 1];
    const u16* Vc = Vs[it & 1];

    f32x4 st[4] = {};
#pragma unroll
    for (int kk = 0; kk < 2; kk++)
#pragma unroll
      for (int i = 0; i < 4; i++) {
        const int pos = (kk * 4 + q) ^ (li & 7);
        const bf16x8 kf = *(const bf16x8*)&Kc[(i * 16 + li) * 64 + pos * 8];
        st[i] = __builtin_amdgcn_mfma_f32_16x16x32_bf16(kf, qf[kk], st[i], 0, 0, 0);
      }

    u32 pk[4][2];
#pragma unroll
    for (int i = 0; i < 4; i++) {
      const float p0 = fexp2(st[i][0]);
      const float p1 = fexp2(st[i][1]);
      const float p2 = fexp2(st[i][2]);
      const float p3 = fexp2(st[i][3]);
      lsum += (p0 + p1) + (p2 + p3);
      pk[i][0] = packtrunc(p0, p1);
      pk[i][1] = packtrunc(p2, p3);
    }

#pragma unroll
    for (int i = 0; i < 4; i++) {
      const int a = li * 72 + i * 16 + q * 4;
      *(u32*)&Pw[a]     = pk[i][0];
      *(u32*)&Pw[a + 2] = pk[i][1];
    }

#pragma unroll
    for (int kk = 0; kk < 2; kk++) {
      const bf16x8 pf = *(const bf16x8*)&Pw[li * 72 + kk * 32 + q * 8];
#pragma unroll
      for (int m = 0; m < 4; m++) {
        const int pos = (kk * 4 + q) ^ (li & 7);
        const bf16x8 vf = *(const bf16x8*)&Vc[(m * 16 + li) * 64 + pos * 8];
        ot[m] = __builtin_amdgcn_mfma_f32_16x16x32_bf16(vf, pf, ot[m], 0, 0, 0);
      }
    }
  }

  float s = lsum;
  s += __shfl_xor(s, 16);
  s += __shfl_xor(s, 32);
  const float inv = 1.f / s;
#pragma unroll
  for (int m = 0; m < 4; m++) {
    const int a = li * 72 + m * 16 + q * 4;
    *(u32*)&Pw[a]     = packtrunc(ot[m][0] * inv, ot[m][1] * inv);
    *(u32*)&Pw[a + 2] = packtrunc(ot[m][2] * inv, ot[m][3] * inv);
  }
#pragma unroll
  for (int pass = 0; pass < 2; pass++) {
    const int row = pass * 8 + lr8;
    const bf16x8 v = *(const bf16x8*)&Pw[row * 72 + lc8 * 8];
    const int token = q0 + w * 16 + row;
    *(bf16x8*)(ob + ((size_t)(b * TT + token) * NH + h) * DH + lc8 * 8) = v;
  }
}

// ---------------------------------------------------------------------------
extern "C" void kernel_launch(void* const* d_in, const int* in_sizes, int n_in,
                              void* d_out, int out_size, void* d_ws, size_t ws_size,
                              hipStream_t stream) {
  const float* x    = (const float*)d_in[0];
  const float* wq   = (const float*)d_in[1];
  const float* wk   = (const float*)d_in[2];
  const float* wv   = (const float*)d_in[3];
  const float* wo   = (const float*)d_in[4];
  const float* w1   = (const float*)d_in[5];
  const float* b1   = (const float*)d_in[6];
  const float* w2   = (const float*)d_in[7];
  const float* b2   = (const float*)d_in[8];
  const float* ln1g = (const float*)d_in[9];
  const float* ln1b = (const float*)d_in[10];
  const float* ln2g = (const float*)d_in[11];
  const float* ln2b = (const float*)d_in[12];

  size_t off = 0;
  char* base = (char*)d_ws;
  auto alloc = [&](size_t bytes) { void* p = base + off; off += bytes; return p; };

  u16* wqkv_b = (u16*)alloc((size_t)3 * DM * DM * 2);   // [3072,1024]
  u16* wo_b   = (u16*)alloc((size_t)DM * DM * 2);
  u16* w1_b   = (u16*)alloc((size_t)DFF * DM * 2);
  u16* w2_b   = (u16*)alloc((size_t)DM * DFF * 2);
  u16* h1     = (u16*)alloc((size_t)MTOK * DM * 2);     // 8 MB
  u16* qkvb   = (u16*)alloc((size_t)MTOK * QS * 2);     // 24 MB
  u16* attn   = (u16*)alloc((size_t)MTOK * DM * 2);     // 8 MB
  u16* h2     = (u16*)alloc((size_t)MTOK * DM * 2);     // 8 MB
  u16* ff1    = (u16*)alloc((size_t)MTOK * DFF * 2);    // 32 MB
  float* xmid = (float*)alloc((size_t)MTOK * DM * 4);
  u16* vtb    = ff1;           // V^T: used (transpose->attn) before ff1 written
  u16* woP    = ff1;           // WO bf16 partials (2x8MB): dead before FF1
  u16* ff2P   = h1;            // FF2 bf16 partials (2x8MB: h1+qkvb head, dead)
  (void)ws_size; (void)in_sizes; (void)n_in; (void)out_size;

  // all weight conversions + LN1 in one dispatch
  prep<<<13312, 256, 0, stream>>>(wq, wk, wv, wo, w1, w2, x, ln1g, ln1b,
                                  wqkv_b, wo_b, w1_b, w2_b, h1);

  // fused QKV projection (XCD-swizzled 1D grid); q cols pre-scaled
  const float QSCALE = 0.125f * 1.44269504088896340736f;
  gemm_bt<0, 128><<<(QS / 128) * (MTOK / 128), 256, 0, stream>>>(
      h1, wqkv_b, MTOK, QS, DM, nullptr, qkvb, QSCALE, DM, QS / 128, MTOK / 128);

  // V transpose per head (XCD-grouped), then MFMA flash attention (8 waves)
  transpose_v<<<dim3(BB * NH, TT / 64), 256, 0, stream>>>(qkvb + 2 * DM, vtb);
  attn_mfma<<<dim3(BB * NH, TT / 128), 512, 0, stream>>>(qkvb, qkvb + DM, vtb, attn);

  // out-proj, split-K=2 -> bf16 partials; fused reduce + residual + LN2
  gemm_sk<<<(DM / 64) * (MTOK / 128) * 2, 256, 0, stream>>>(
      attn, wo_b, DM, DM, DM / 2, woP, DM / 64, MTOK / 128);
  reduce_ln<<<MTOK / 4, 256, 0, stream>>>(x, woP, ln2g, ln2b, xmid, h2);

  // FFN: FF1 (gelu fused), FF2 split-K=2 (bf16 partials) + fused reduce
  gemm_bt<2, 128><<<(DFF / 128) * (MTOK / 128), 256, 0, stream>>>(
      h2, w1_b, MTOK, DFF, DM, b1, ff1, 1.f, 0, DFF / 128, MTOK / 128);
  gemm_sk<<<(DM / 64) * (MTOK / 128) * 2, 256, 0, stream>>>(
      ff1, w2_b, DM, DFF, DFF / 2, ff2P, DM / 64, MTOK / 128);
  reduce_out<<<MTOK * DM / 4 / 256, 256, 0, stream>>>(ff2P, xmid, b2, (float*)d_out);
}